// Round 5
// baseline (136.924 us; speedup 1.0000x reference)
//
#include <hip/hip_runtime.h>
#include <hip/hip_bf16.h>

// HardAttention = GEMM out=tanh([ctx|outp]@W^T+b) (M=16384,K=1024,N=512, bf16 MFMA)
//               + attn = constant one-hot [4,4096,4096] (256 MiB write stream).
// Round-4 lesson: hipMemsetAsync(268MB) runs at 1.5 TB/s (fixed per-thread work, small grid).
// Round 5: (1) own grid-stride NT-store fill w/ computed one-hot (no memset, no diag kernel);
//          (2) GEMM LDS double-buffered, next-tile loads issued before MFMA, 1 barrier/iter;
//          (3) tile remap mt=bid&127 so the 4 A-panel sharers land on one XCD (bids 128 apart).

typedef __attribute__((ext_vector_type(8))) short bf16x8;   // 8 bf16 = 4 VGPRs
typedef __attribute__((ext_vector_type(4))) float f32x4;

#define B_N 4
#define L_N 4096
#define S_N 4096
#define D_N 512
#define M_N (B_N * L_N)   // 16384
#define K_N (2 * D_N)     // 1024

#define BM 128
#define BN 128
#define GEMM_BLOCKS ((M_N / BM) * (D_N / BN))  // 512
#define NTHREADS 256

#define FILL_BLOCKS 2048
#define FILL_ITERS 32   // 16,777,216 float4s / (2048*256) threads

static __device__ __forceinline__ short f2bf(float f) {
  unsigned u = __builtin_bit_cast(unsigned, f);
  u += 0x7fffu + ((u >> 16) & 1u);   // RNE
  return (short)(u >> 16);
}

static __device__ __forceinline__ bf16x8 pack8(f32x4 a, f32x4 b) {
  bf16x8 r;
  r[0] = f2bf(a.x); r[1] = f2bf(a.y); r[2] = f2bf(a.z); r[3] = f2bf(a.w);
  r[4] = f2bf(b.x); r[5] = f2bf(b.y); r[6] = f2bf(b.z); r[7] = f2bf(b.w);
  return r;
}

// ---------------- GEMM: out = tanh(A @ W^T + b), double-buffered LDS ----------------
// A[m,k] = (k<512) ? ctx[m*512+k] : outp[m*512+k-512]
__global__ __launch_bounds__(NTHREADS, 2)
void gemm_tanh(const float* __restrict__ outp, const float* __restrict__ ctx,
               const float* __restrict__ W, const float* __restrict__ bias,
               float* __restrict__ dout)
{
  __shared__ char As[2][16384];
  __shared__ char Bs[2][16384];

  const int bid = blockIdx.x;
  const int tid = threadIdx.x;
  const int mt = bid & 127;           // A-panel sharers are 128 apart -> same XCD (128%8==0)
  const int nt = bid >> 7;
  const int row0 = mt * BM;
  const int col0 = nt * BN;
  const int lane = tid & 63;
  const int wid  = tid >> 6;
  const int wr = (wid >> 1) * 64;     // wave 64x64 sub-tile
  const int wc = (wid & 1) * 64;

  f32x4 acc[4][4] = {};

  // staging: thread -> row sr (0..127), half sh (cols [sh,sh+32) of the 64-col k-tile)
  const int sr = tid >> 1;
  const int sh = (tid & 1) * 32;
  const float* aRow  = ctx  + (size_t)(row0 + sr) * D_N;   // k-tiles 0..7
  const float* aRow2 = outp + (size_t)(row0 + sr) * D_N;   // k-tiles 8..15
  const float* bRowW = W + (size_t)(col0 + sr) * K_N;
  const int wbase = sr * 128;
  const int wswz  = (sr & 7) << 4;

  f32x4 a4[8], b4[8];

  // ---- prologue: tile 0 -> LDS buf 0 ----
#pragma unroll
  for (int q = 0; q < 8; ++q) a4[q] = ((const f32x4*)(aRow + sh))[q];
#pragma unroll
  for (int q = 0; q < 8; ++q) b4[q] = ((const f32x4*)(bRowW + sh))[q];
#pragma unroll
  for (int q = 0; q < 4; ++q) {
    const int kb = sh * 2 + q * 16;
    *(bf16x8*)&As[0][wbase + (kb ^ wswz)] = pack8(a4[2 * q], a4[2 * q + 1]);
    *(bf16x8*)&Bs[0][wbase + (kb ^ wswz)] = pack8(b4[2 * q], b4[2 * q + 1]);
  }
  __syncthreads();

#pragma unroll 2
  for (int kt = 0; kt < 16; ++kt) {
    const int cur = kt & 1;
    // ---- issue next tile's global loads BEFORE compute (latency hides under MFMA) ----
    if (kt < 15) {
      const int kn = kt + 1;
      const float* ap = ((kn < 8) ? aRow : aRow2) + ((kn & 7) * 64 + sh);
      const float* bp = bRowW + (kn * 64 + sh);
#pragma unroll
      for (int q = 0; q < 8; ++q) a4[q] = ((const f32x4*)ap)[q];
#pragma unroll
      for (int q = 0; q < 8; ++q) b4[q] = ((const f32x4*)bp)[q];
    }

    // ---- compute on buf[cur] ----
#pragma unroll
    for (int kk = 0; kk < 2; ++kk) {
      const int kb = kk * 64 + ((lane >> 4) << 4);
      bf16x8 af[4], bfr[4];
#pragma unroll
      for (int i = 0; i < 4; ++i) {
        const int ar = wr + i * 16 + (lane & 15);
        af[i]  = *(const bf16x8*)&As[cur][ar * 128 + (kb ^ ((ar & 7) << 4))];
        const int br = wc + i * 16 + (lane & 15);
        bfr[i] = *(const bf16x8*)&Bs[cur][br * 128 + (kb ^ ((br & 7) << 4))];
      }
#pragma unroll
      for (int i = 0; i < 4; ++i)
#pragma unroll
        for (int j = 0; j < 4; ++j)
          acc[i][j] = __builtin_amdgcn_mfma_f32_16x16x32_bf16(af[i], bfr[j], acc[i][j], 0, 0, 0);
    }

    // ---- pack + write next tile into the other buffer ----
    if (kt < 15) {
#pragma unroll
      for (int q = 0; q < 4; ++q) {
        const int kb = sh * 2 + q * 16;
        *(bf16x8*)&As[cur ^ 1][wbase + (kb ^ wswz)] = pack8(a4[2 * q], a4[2 * q + 1]);
        *(bf16x8*)&Bs[cur ^ 1][wbase + (kb ^ wswz)] = pack8(b4[2 * q], b4[2 * q + 1]);
      }
    }
    __syncthreads();
  }

  // epilogue: C/D layout col=lane&15, row=(lane>>4)*4+reg (verified m89/m91)
  const int r0  = row0 + wr + ((lane >> 4) << 2);
  const int c0g = col0 + wc + (lane & 15);
  float bv[4];
#pragma unroll
  for (int j = 0; j < 4; ++j) bv[j] = bias[c0g + j * 16];
#pragma unroll
  for (int i = 0; i < 4; ++i)
#pragma unroll
    for (int j = 0; j < 4; ++j)
#pragma unroll
      for (int r = 0; r < 4; ++r) {
        const int m = r0 + i * 16 + r;
        const int n = c0g + j * 16;
        dout[(size_t)m * D_N + n] = tanhf(acc[i][j][r] + bv[j]);
      }
}

// ---------------- attn fill: computed one-hot, NT float4 stores ----------------
__global__ __launch_bounds__(NTHREADS)
void fill_attn(float* __restrict__ dout)
{
  float* attn = dout + (size_t)M_N * D_N;
  const int i0 = blockIdx.x * NTHREADS + threadIdx.x;
  const int stride = FILL_BLOCKS * NTHREADS;
#pragma unroll
  for (int k = 0; k < FILL_ITERS; ++k) {
    const int i = i0 + k * stride;                 // float4 index, exact cover
    const int f = i << 2;                          // flat float index < 2^26
    const int col = f & (S_N - 1);
    const int l   = (f >> 12) & (L_N - 1);
    f32x4 v;
    v.x = (col     == l) ? 1.0f : 0.0f;
    v.y = (col + 1 == l) ? 1.0f : 0.0f;
    v.z = (col + 2 == l) ? 1.0f : 0.0f;
    v.w = (col + 3 == l) ? 1.0f : 0.0f;
    __builtin_nontemporal_store(v, (f32x4*)attn + i);
  }
}

extern "C" void kernel_launch(void* const* d_in, const int* in_sizes, int n_in,
                              void* d_out, int out_size, void* d_ws, size_t ws_size,
                              hipStream_t stream) {
  const float* outp = (const float*)d_in[0];
  const float* ctx  = (const float*)d_in[1];
  const float* W    = (const float*)d_in[2];
  const float* bias = (const float*)d_in[3];
  float* dout = (float*)d_out;
  hipLaunchKernelGGL(gemm_tanh, dim3(GEMM_BLOCKS), dim3(NTHREADS), 0, stream,
                     outp, ctx, W, bias, dout);
  hipLaunchKernelGGL(fill_attn, dim3(FILL_BLOCKS), dim3(NTHREADS), 0, stream, dout);
}

// Round 6
// 106.926 us; speedup vs baseline: 1.2805x; 1.2805x over previous
//
#include <hip/hip_runtime.h>
#include <hip/hip_bf16.h>

// HardAttention = GEMM out=tanh([ctx|outp]@W^T+b) (M=16384,K=1024,N=512, bf16 MFMA)
//               + attn = constant one-hot [4,4096,4096] (256 MiB write stream).
// Round-5 lesson: explicit dbuf+prefetch GEMM regressed (likely VGPR spill under unroll);
// round-2 lesson: dedicated fill blocks starve the lockstep GEMM (unbounded store queues).
// Round 6: ONE kernel. The GEMM waves themselves emit the fill: 8 NT float4 stores per
// thread per K-step (exact 268MB cover), bounded to 64KB/CU in flight, retired by each
// step's vmcnt(0) barrier drain -> the store stream runs inside the GEMM's stall windows.

typedef __attribute__((ext_vector_type(8))) short bf16x8;   // 8 bf16 = 4 VGPRs
typedef __attribute__((ext_vector_type(4))) float f32x4;

#define B_N 4
#define L_N 4096
#define S_N 4096
#define D_N 512
#define M_N (B_N * L_N)   // 16384
#define K_N (2 * D_N)     // 1024

#define BM 128
#define BN 128
#define GEMM_BLOCKS ((M_N / BM) * (D_N / BN))  // 512
#define NTHREADS 256

static __device__ __forceinline__ short f2bf(float f) {
  unsigned u = __builtin_bit_cast(unsigned, f);
  u += 0x7fffu + ((u >> 16) & 1u);   // RNE
  return (short)(u >> 16);
}

static __device__ __forceinline__ bf16x8 pack8(f32x4 a, f32x4 b) {
  bf16x8 r;
  r[0] = f2bf(a.x); r[1] = f2bf(a.y); r[2] = f2bf(a.z); r[3] = f2bf(a.w);
  r[4] = f2bf(b.x); r[5] = f2bf(b.y); r[6] = f2bf(b.z); r[7] = f2bf(b.w);
  return r;
}

// ---------------- fused GEMM + attn fill ----------------
// A[m,k] = (k<512) ? ctx[m*512+k] : outp[m*512+k-512]
__global__ __launch_bounds__(NTHREADS, 2)
void gemm_fill(const float* __restrict__ outp, const float* __restrict__ ctx,
               const float* __restrict__ W, const float* __restrict__ bias,
               float* __restrict__ dout)
{
  __shared__ char As[128 * 128];
  __shared__ char Bs[128 * 128];

  const int bid = blockIdx.x;
  const int tid = threadIdx.x;
  const int mt = bid >> 2;            // 4 consecutive blocks share the A panel
  const int nt = bid & 3;
  const int row0 = mt * BM;
  const int col0 = nt * BN;
  const int lane = tid & 63;
  const int wid  = tid >> 6;
  const int wr = (wid >> 1) * 64;     // wave 64x64 sub-tile
  const int wc = (wid & 1) * 64;

  float* attn = dout + (size_t)M_N * D_N;   // one-hot region, disjoint from C and inputs

  f32x4 acc[4][4] = {};

  // staging: thread -> row sr (0..127), half sh (cols [sh,sh+32) of the 64-col k-tile)
  const int sr = tid >> 1;
  const int sh = (tid & 1) * 32;
  const float* bRowW = W + (size_t)(col0 + sr) * K_N;

  for (int kt = 0; kt < 16; ++kt) {
    const float* ap = ((kt < 8) ? ctx : outp) + (size_t)(row0 + sr) * D_N + ((kt & 7) * 64 + sh);
    const float* bp = bRowW + (kt * 64 + sh);
    f32x4 a4[8], b4[8];
#pragma unroll
    for (int q = 0; q < 8; ++q) a4[q] = ((const f32x4*)ap)[q];
#pragma unroll
    for (int q = 0; q < 8; ++q) b4[q] = ((const f32x4*)bp)[q];

    // ---- fill slice: 8 NT float4 stores/thread/step; exact bijective cover of 268MB.
    // Per (bid,kt,q): 256 threads store 4KB contiguous. Independent of loads above;
    // retired by this step's pre-barrier vmcnt(0) drain (self-throttled, 64KB/CU max).
#pragma unroll
    for (int q = 0; q < 8; ++q) {
      const int i = (((bid * 16 + kt) * 8 + q) << 8) + tid;  // float4 index < 2^24
      const int f = i << 2;                                  // flat float index
      const int col = f & (S_N - 1);
      const int l   = (f >> 12) & (L_N - 1);
      f32x4 v;
      v.x = (col     == l) ? 1.0f : 0.0f;
      v.y = (col + 1 == l) ? 1.0f : 0.0f;
      v.z = (col + 2 == l) ? 1.0f : 0.0f;
      v.w = (col + 3 == l) ? 1.0f : 0.0f;
      __builtin_nontemporal_store(v, (f32x4*)attn + i);
    }

    bf16x8 pa[4], pb[4];
#pragma unroll
    for (int q = 0; q < 4; ++q) {
      pa[q] = pack8(a4[2 * q], a4[2 * q + 1]);
      pb[q] = pack8(b4[2 * q], b4[2 * q + 1]);
    }
    __syncthreads();   // previous tile's reads done
    {
      const int wbase = sr * 128;
      const int wswz  = (sr & 7) << 4;
#pragma unroll
      for (int q = 0; q < 4; ++q) {
        const int kb = sh * 2 + q * 16;          // byte offset within 128B row
        *(bf16x8*)&As[wbase + (kb ^ wswz)] = pa[q];
        *(bf16x8*)&Bs[wbase + (kb ^ wswz)] = pb[q];
      }
    }
    __syncthreads();   // tile ready

#pragma unroll
    for (int kk = 0; kk < 2; ++kk) {
      const int kb = kk * 64 + ((lane >> 4) << 4);
      bf16x8 af[4], bfr[4];
#pragma unroll
      for (int i = 0; i < 4; ++i) {
        const int ar = wr + i * 16 + (lane & 15);
        af[i]  = *(const bf16x8*)&As[ar * 128 + (kb ^ ((ar & 7) << 4))];
        const int br = wc + i * 16 + (lane & 15);
        bfr[i] = *(const bf16x8*)&Bs[br * 128 + (kb ^ ((br & 7) << 4))];
      }
#pragma unroll
      for (int i = 0; i < 4; ++i)
#pragma unroll
        for (int j = 0; j < 4; ++j)
          acc[i][j] = __builtin_amdgcn_mfma_f32_16x16x32_bf16(af[i], bfr[j], acc[i][j], 0, 0, 0);
    }
  }

  // epilogue: C/D layout col=lane&15, row=(lane>>4)*4+reg (verified m89/m91)
  const int r0  = row0 + wr + ((lane >> 4) << 2);
  const int c0g = col0 + wc + (lane & 15);
  float bv[4];
#pragma unroll
  for (int j = 0; j < 4; ++j) bv[j] = bias[c0g + j * 16];
#pragma unroll
  for (int i = 0; i < 4; ++i)
#pragma unroll
    for (int j = 0; j < 4; ++j)
#pragma unroll
      for (int r = 0; r < 4; ++r) {
        const int m = r0 + i * 16 + r;
        const int n = c0g + j * 16;
        dout[(size_t)m * D_N + n] = tanhf(acc[i][j][r] + bv[j]);
      }
}

extern "C" void kernel_launch(void* const* d_in, const int* in_sizes, int n_in,
                              void* d_out, int out_size, void* d_ws, size_t ws_size,
                              hipStream_t stream) {
  const float* outp = (const float*)d_in[0];
  const float* ctx  = (const float*)d_in[1];
  const float* W    = (const float*)d_in[2];
  const float* bias = (const float*)d_in[3];
  float* dout = (float*)d_out;
  hipLaunchKernelGGL(gemm_fill, dim3(GEMM_BLOCKS), dim3(NTHREADS), 0, stream,
                     outp, ctx, W, bias, dout);
}

// Round 7
// 79.014 us; speedup vs baseline: 1.7329x; 1.3533x over previous
//
#include <hip/hip_runtime.h>
#include <hip/hip_bf16.h>

// HardAttention = GEMM out=tanh([ctx|outp]@W^T+b) (M=16384,K=1024,N=512, bf16 MFMA)
//               + attn = constant one-hot [4,4096,4096] (256 MiB write stream).
// Round-6 lesson: any s_barrier forces vmcnt(0) -> fill stores serialize into the K-steps.
// Round 7: BARRIER-FREE. Each wave owns a 64x64x1024 tile, staging A/W through per-wave
// private LDS (same-wave ds_write->lgkmcnt->ds_read needs no s_barrier). Fill stores are
// issued every step and never force-drained; staging loads complete via counted vmcnt.
// 2048 waves = 256 mtiles x 8 ntiles; fill = 4 NT float4 stores/lane/step (exact 268MB).

typedef __attribute__((ext_vector_type(8))) short bf16x8;   // 8 bf16 = 4 VGPRs
typedef __attribute__((ext_vector_type(4))) float f32x4;

#define B_N 4
#define L_N 4096
#define S_N 4096
#define D_N 512
#define M_N (B_N * L_N)   // 16384
#define K_N (2 * D_N)     // 1024

#define NTHREADS 256      // 4 waves/block
#define NBLOCKS 512       // 2048 waves total
#define NSTEPS 32         // K / 32

static __device__ __forceinline__ short f2bf(float f) {
  unsigned u = __builtin_bit_cast(unsigned, f);
  u += 0x7fffu + ((u >> 16) & 1u);   // RNE
  return (short)(u >> 16);
}

static __device__ __forceinline__ bf16x8 pack8(f32x4 a, f32x4 b) {
  bf16x8 r;
  r[0] = f2bf(a.x); r[1] = f2bf(a.y); r[2] = f2bf(a.z); r[3] = f2bf(a.w);
  r[4] = f2bf(b.x); r[5] = f2bf(b.y); r[6] = f2bf(b.z); r[7] = f2bf(b.w);
  return r;
}

__global__ __launch_bounds__(NTHREADS, 2)
void gemm_fill(const float* __restrict__ outp, const float* __restrict__ ctx,
               const float* __restrict__ Wm, const float* __restrict__ bias,
               float* __restrict__ dout)
{
  // per-wave private LDS: A-scratch 4KB + W-scratch 4KB (64 rows x 32k bf16 each)
  __shared__ char lds[4][8192];

  const int tid  = threadIdx.x;
  const int lane = tid & 63;
  const int wid  = tid >> 6;
  const int gwave = blockIdx.x * 4 + wid;
  const int mtile = gwave >> 3;       // 256 tiles of 64 rows
  const int ntile = gwave & 7;        // 8 tiles of 64 cols
  const int m0 = mtile * 64;
  const int n0 = ntile * 64;

  char* As = lds[wid];
  char* Ws = lds[wid] + 4096;

  // staging: load q (0..3): local row lr = 16q + lrq, k-chunk ch (8 floats)
  const int lrq = lane >> 2;          // 0..15
  const int ch  = lane & 3;           // 0..3
  // LDS row = 64B (32 bf16). Swizzle: slot ^= ((row>>1)&3)<<4  -> exact 2-way banking
  // (free, m136) on both the write sweep (64 lanes = rows 0..15 x 4 chunks) and the
  // frag read (16 rows x 4 k-groups).
  const int wrB  = lrq * 64 + ((ch << 4) ^ (((lrq >> 1) & 3) << 4));       // + q*1024
  const int rdB  = (lane & 15) * 64 +
                   ((((lane >> 4) << 4)) ^ ((((lane & 15) >> 1) & 3) << 4)); // + i*1024

  // global staging bases (per-lane): A row m0+16q+lrq, W col n0+16q+lrq
  const float* aC = ctx  + (size_t)(m0 + lrq) * D_N + ch * 8;   // k-steps 0..15
  const float* aO = outp + (size_t)(m0 + lrq) * D_N + ch * 8;   // k-steps 16..31
  const float* wB = Wm   + (size_t)(n0 + lrq) * K_N + ch * 8;   // full k

  // fill: this wave covers f32x4 indices [gwave*8192, (gwave+1)*8192)
  f32x4* attn4 = (f32x4*)(dout + (size_t)M_N * D_N) + (size_t)gwave * (NSTEPS * 256);

  f32x4 acc[4][4] = {};
  f32x4 sa[8], sw[8];

  // ---- prologue: issue loads for step 0 ----
#pragma unroll
  for (int q = 0; q < 4; ++q) {
    sa[2*q]   = *(const f32x4*)(aC + q * (16 * D_N));
    sa[2*q+1] = *(const f32x4*)(aC + q * (16 * D_N) + 4);
    sw[2*q]   = *(const f32x4*)(wB + q * (16 * K_N));
    sw[2*q+1] = *(const f32x4*)(wB + q * (16 * K_N) + 4);
  }

#pragma unroll 1
  for (int t = 0; t < NSTEPS; ++t) {
    // ---- pack + ds_write staged data of step t (compiler waits the loads via
    //      counted vmcnt; previously-issued fill stores keep flying) ----
#pragma unroll
    for (int q = 0; q < 4; ++q) {
      *(bf16x8*)(As + q * 1024 + wrB) = pack8(sa[2*q], sa[2*q+1]);
      *(bf16x8*)(Ws + q * 1024 + wrB) = pack8(sw[2*q], sw[2*q+1]);
    }

    // ---- issue step t+1 loads (staging regs are free again) ----
    if (t + 1 < NSTEPS) {
      const int tn = t + 1;
      const float* ab = (tn < 16 ? aC : aO) + (tn & 15) * 32;
      const float* wb = wB + tn * 32;
#pragma unroll
      for (int q = 0; q < 4; ++q) {
        sa[2*q]   = *(const f32x4*)(ab + q * (16 * D_N));
        sa[2*q+1] = *(const f32x4*)(ab + q * (16 * D_N) + 4);
        sw[2*q]   = *(const f32x4*)(wb + q * (16 * K_N));
        sw[2*q+1] = *(const f32x4*)(wb + q * (16 * K_N) + 4);
      }
    }

    // ---- fill slice for step t: 4 NT float4 stores/lane, never force-drained ----
#pragma unroll
    for (int s = 0; s < 4; ++s) {
      const int gi = gwave * (NSTEPS * 256) + t * 256 + (s << 6) + lane; // f32x4 idx
      const int col4 = (gi & 1023) << 2;          // (gi*4) & 4095
      const int l    = (gi >> 10) & 4095;         // ((gi*4) >> 12) & 4095
      f32x4 v;
      v.x = (col4     == l) ? 1.0f : 0.0f;
      v.y = (col4 + 1 == l) ? 1.0f : 0.0f;
      v.z = (col4 + 2 == l) ? 1.0f : 0.0f;
      v.w = (col4 + 3 == l) ? 1.0f : 0.0f;
      __builtin_nontemporal_store(v, attn4 + (t * 256 + (s << 6) + lane));
    }

    // ---- fragments (lgkmcnt-counted, same wave) + 16 MFMA ----
    bf16x8 af[4], wf[4];
#pragma unroll
    for (int i = 0; i < 4; ++i) {
      af[i] = *(const bf16x8*)(As + i * 1024 + rdB);
      wf[i] = *(const bf16x8*)(Ws + i * 1024 + rdB);
    }
#pragma unroll
    for (int i = 0; i < 4; ++i)
#pragma unroll
      for (int j = 0; j < 4; ++j)
        acc[i][j] = __builtin_amdgcn_mfma_f32_16x16x32_bf16(af[i], wf[j], acc[i][j], 0, 0, 0);
  }

  // ---- epilogue: C/D layout col=lane&15, row=(lane>>4)*4+reg (verified R1/m89/m91) ----
  const int r0  = m0 + ((lane >> 4) << 2);
  const int c0g = n0 + (lane & 15);
  float bv[4];
#pragma unroll
  for (int j = 0; j < 4; ++j) bv[j] = bias[c0g + j * 16];
#pragma unroll
  for (int i = 0; i < 4; ++i)
#pragma unroll
    for (int j = 0; j < 4; ++j)
#pragma unroll
      for (int r = 0; r < 4; ++r) {
        const int m = r0 + i * 16 + r;
        const int n = c0g + j * 16;
        dout[(size_t)m * D_N + n] = tanhf(acc[i][j][r] + bv[j]);
      }
}

extern "C" void kernel_launch(void* const* d_in, const int* in_sizes, int n_in,
                              void* d_out, int out_size, void* d_ws, size_t ws_size,
                              hipStream_t stream) {
  const float* outp = (const float*)d_in[0];
  const float* ctx  = (const float*)d_in[1];
  const float* Wm   = (const float*)d_in[2];
  const float* bias = (const float*)d_in[3];
  float* dout = (float*)d_out;
  hipLaunchKernelGGL(gemm_fill, dim3(NBLOCKS), dim3(NTHREADS), 0, stream,
                     outp, ctx, Wm, bias, dout);
}